// Round 11
// baseline (72.853 us; speedup 1.0000x reference)
//
#include <hip/hip_runtime.h>
#include <hip/hip_bf16.h>

#define BB 4
#define CC 64
#define HH 256
#define WW 256
#define KK 9
#define NOFF 18
#define HO 254
#define WO 254
#define NPIX (HO*WO)           // 64516

// ---------------- workspace layout ----------------
#define WS_W    0
#define WS_OFF  32768
#define WS_Y    (WS_OFF + BB*NOFF*NPIX*4)           // 18,613,376
#define WS_NEED (WS_Y + BB*KK*HH*WW*4)              // 28,050,560  (mid path)
#define WS_XT   WS_NEED
#define WS_NEED2 (WS_XT + (size_t)BB*HH*WW*CC*2)    // 61,604,992  (fast path)

#define SWZ(lin) ((lin) ^ ((((lin) >> 7) & 7) << 4))

typedef __attribute__((ext_vector_type(8))) short bf16x8;
typedef __attribute__((ext_vector_type(4))) float f32x4;

static __device__ __forceinline__ unsigned short f2bf(float v) {
    __hip_bfloat16 h = __float2bfloat16(v);
    union { __hip_bfloat16 b; unsigned short u; } cv; cv.b = h; return cv.u;
}

static __device__ __forceinline__ void repack_piece(
    int tap, int tid, int nthr,
    const float* __restrict__ offset_w,
    const float* __restrict__ deform_w,
    unsigned char* __restrict__ ws)
{
    if (tap < 9) {
        for (int i = tid; i < 18 * 64; i += nthr) {
            int o = i >> 6;
            int c = i & 63;
            int row = tap * 18 + o;
            unsigned int byte = (unsigned)(row * 128 + c * 2) ^ (((unsigned)(row & 7)) << 4);
            *(unsigned short*)(ws + WS_W + byte) = f2bf(offset_w[((size_t)o * CC + c) * KK + tap]);
        }
    } else {
        for (int i = tid; i < 16 * 64; i += nthr) {
            int t = i >> 6;
            int c = i & 63;
            float v = (t < KK) ? deform_w[(size_t)c * KK + t] : 0.0f;
            unsigned int byte = (unsigned)(t * 128 + c * 2) ^ (((unsigned)(t & 7)) << 4);
            *(unsigned short*)(ws + WS_W + 20736 + byte) = f2bf(v);
        }
    }
}

// ================= kernel W: standalone repack (mid path only) =================
__global__ __launch_bounds__(256) void repack_kernel(
    const float* __restrict__ offset_w,
    const float* __restrict__ deform_w,
    unsigned char* __restrict__ ws)
{
    repack_piece(blockIdx.x, threadIdx.x, 256, offset_w, deform_w, ws);
}

// ========== kernel P: x NCHW f32 -> xT NHWC bf16 (+ fused weight repack) ==========
__global__ __launch_bounds__(256) void transpose_kernel(
    const float* __restrict__ x,
    unsigned short* __restrict__ xT,
    const float* __restrict__ offset_w,
    const float* __restrict__ deform_w,
    unsigned char* __restrict__ ws)
{
    __shared__ float s[64][65];
    const int tid = threadIdx.x;
    const int w0 = blockIdx.x * 64;
    const int h  = blockIdx.y;
    const int b  = blockIdx.z;

    // fused one-time weight repack on 10 designated blocks
    if (b == 0 && blockIdx.x == 0 && h < 10)
        repack_piece(h, tid, 256, offset_w, deform_w, ws);

    #pragma unroll
    for (int it = 0; it < 4; ++it) {
        int i  = tid + it * 256;            // 0..1023
        int c  = i >> 4;
        int p4 = (i & 15) << 2;
        float4 v = *(const float4*)(x + (((size_t)b * CC + c) * HH + h) * WW + w0 + p4);
        s[c][p4 + 0] = v.x; s[c][p4 + 1] = v.y; s[c][p4 + 2] = v.z; s[c][p4 + 3] = v.w;
    }
    __syncthreads();
    #pragma unroll
    for (int it = 0; it < 2; ++it) {
        int j  = tid + it * 256;            // 0..511
        int px = j >> 3;
        int g  = j & 7;
        unsigned int u[4];
        #pragma unroll
        for (int q = 0; q < 4; ++q) {
            __hip_bfloat162 h2 = __float22bfloat162_rn(
                make_float2(s[g * 8 + 2 * q][px], s[g * 8 + 2 * q + 1][px]));
            __builtin_memcpy(&u[q], &h2, 4);
        }
        unsigned short* dst = xT + (((size_t)b * HH + h) * WW + w0 + px) * 64 + g * 8;
        *(uint4*)dst = make_uint4(u[0], u[1], u[2], u[3]);
    }
}

// ============ kernel C2: wave-autonomous conv + Y, A-frags direct from xT ============
// 512 blocks x 1024 threads (16 waves); per wave: 2x16-pixel tile
__global__ __launch_bounds__(1024) void convY_direct(
    const unsigned short* __restrict__ xT,
    const float* __restrict__ offset_b,
    const unsigned char* __restrict__ ws_w,
    float* __restrict__ off,      // [B][18][NPIX]
    float* __restrict__ Y)        // [B][9][HH*WW]
{
    __shared__ __align__(16) unsigned char smem[22784];
    const int tid = threadIdx.x;

    {   // stage swizzled weights once per block (amortized over 16 waves)
        const uint4* src = (const uint4*)ws_w;
        uint4* dst = (uint4*)smem;
        for (int i = tid; i < 1424; i += 1024) dst[i] = src[i];
    }
    __syncthreads();   // the only barrier

    const int wv = tid >> 6;                    // 0..15
    const int l  = tid & 63;
    const int lr = l & 15;
    const int lk = l >> 4;

    const int gtile = blockIdx.x * 16 + wv;     // 0..8191
    const int tb  = gtile >> 11;                // batch
    const int rem = gtile & 2047;
    const int y0  = (rem >> 4) * 2;             // 0,2,..,254
    const int x0  = (rem & 15) * 16;

    const unsigned char* xb = (const unsigned char*)(xT + (size_t)tb * HH * WW * 64);

    const int o1 = (16 + lr > 17) ? 17 : 16 + lr;
    const float bias0 = offset_b[lr];
    const float bias1 = (lr < 2) ? offset_b[16 + lr] : 0.0f;

    f32x4 accC[2][2];
    f32x4 accY[2];
    #pragma unroll
    for (int mi = 0; mi < 2; ++mi) {
        #pragma unroll
        for (int reg = 0; reg < 4; ++reg) { accC[mi][0][reg] = bias0; accC[mi][1][reg] = bias1; }
        accY[mi] = (f32x4){0.f, 0.f, 0.f, 0.f};
    }

    auto ldw = [&](int row, int cbyte) -> bf16x8 {
        unsigned int byte = (unsigned)(row * 128 + cbyte) ^ (((unsigned)(row & 7)) << 4);
        return *(const bf16x8*)(smem + byte);
    };

    #pragma unroll
    for (int ch = 0; ch < 2; ++ch) {
        const int cbyte = ch * 64 + lk * 16;
        #pragma unroll
        for (int kw = 0; kw < 3; ++kw) {
            const int gx = min(x0 + lr + kw, WW - 1);
            bf16x8 a[4];
            #pragma unroll
            for (int rr = 0; rr < 4; ++rr) {
                const int gy = min(y0 + rr, HH - 1);
                a[rr] = *(const bf16x8*)(xb + (size_t)(gy * WW + gx) * 128 + cbyte);
            }
            if (kw == 0) {
                unsigned int byY = (unsigned)(lr * 128 + cbyte) ^ (((unsigned)(lr & 7)) << 4);
                bf16x8 bY = *(const bf16x8*)(smem + 20736 + byY);
                accY[0] = __builtin_amdgcn_mfma_f32_16x16x32_bf16(a[0], bY, accY[0], 0, 0, 0);
                accY[1] = __builtin_amdgcn_mfma_f32_16x16x32_bf16(a[1], bY, accY[1], 0, 0, 0);
            }
            #pragma unroll
            for (int kh = 0; kh < 3; ++kh) {
                const int tap = kh * 3 + kw;
                bf16x8 b0 = ldw(tap * 18 + lr, cbyte);
                bf16x8 b1 = ldw(tap * 18 + o1, cbyte);
                accC[0][0] = __builtin_amdgcn_mfma_f32_16x16x32_bf16(a[kh],     b0, accC[0][0], 0, 0, 0);
                accC[0][1] = __builtin_amdgcn_mfma_f32_16x16x32_bf16(a[kh],     b1, accC[0][1], 0, 0, 0);
                accC[1][0] = __builtin_amdgcn_mfma_f32_16x16x32_bf16(a[kh + 1], b0, accC[1][0], 0, 0, 0);
                accC[1][1] = __builtin_amdgcn_mfma_f32_16x16x32_bf16(a[kh + 1], b1, accC[1][1], 0, 0, 0);
            }
        }
    }

    // ---- stores: D col(lr)=o/tap, D row(lk*4+reg)=image column ----
    #pragma unroll
    for (int mi = 0; mi < 2; ++mi) {
        const int ho = y0 + mi;
        #pragma unroll
        for (int nt = 0; nt < 2; ++nt) {
            const int o = nt * 16 + lr;
            if (o < NOFF && ho < HO) {
                float* dst = off + ((size_t)tb * NOFF + o) * NPIX + (size_t)ho * WO;
                #pragma unroll
                for (int reg = 0; reg < 4; ++reg) {
                    const int wo = x0 + lk * 4 + reg;
                    if (wo < WO) dst[wo] = accC[mi][nt][reg];
                }
            }
        }
        if (lr < KK) {
            float* dst = Y + ((size_t)tb * KK + lr) * (HH * WW) + (size_t)(y0 + mi) * WW + x0;
            #pragma unroll
            for (int reg = 0; reg < 4; ++reg)
                dst[lk * 4 + reg] = accY[mi][reg];
        }
    }
}

// ================= kernel C (mid path, R9): persistent pipelined conv + Y ============
#define TSH 8
#define TSW 16
#define PTH 10
#define PTW 18
#define NCELLC (PTH*PTW)
#define CHITEM (16*NCELLC)
#define CHITER 12
#define LDS_W   0
#define LDS_B0  22784
#define LDS_B1  34304
#define SMEM_C  45824
#define NT      4
#define NSTEP   (NT*2)

__global__ __launch_bounds__(256) void convY_kernel(
    const float* __restrict__ x,
    const float* __restrict__ offset_b,
    const unsigned char* __restrict__ ws_w,
    float* __restrict__ off,
    float* __restrict__ Y)
{
    __shared__ __align__(16) unsigned char smem[SMEM_C];

    const int tid = threadIdx.x;
    const int bid = blockIdx.x;

    {
        const uint4* src = (const uint4*)ws_w;
        uint4* dst = (uint4*)(smem + LDS_W);
        for (int i = tid; i < 1424; i += 256) dst[i] = src[i];
    }

    const int w  = tid >> 6;
    const int l  = tid & 63;
    const int lr = l & 15;
    const int lk = l >> 4;

    auto tile_of = [&](int s, int& tb, int& tx0, int& ty0) {
        int t4 = bid * NT + (s >> 1);
        tb  = t4 >> 9;
        int rem = t4 & 511;
        ty0 = (rem >> 4) * TSH;
        tx0 = (rem & 15) * TSW;
    };

    float vaA[CHITER], vbA[CHITER], vaB[CHITER], vbB[CHITER];

    auto issue = [&](int s, float* va, float* vb) {
        int tb, tx0, ty0; tile_of(s, tb, tx0, ty0);
        const int cc0 = (s & 1) * 32;
        const float* xb = x + (size_t)tb * CC * HH * WW;
        #pragma unroll
        for (int it = 0; it < CHITER; ++it) {
            int i  = tid + it * 256;
            int ii = (i < CHITEM) ? i : (CHITEM - 1);
            int cpair = ii / NCELLC;
            int cell  = ii - cpair * NCELLC;
            int r   = cell / PTW;
            int col = cell - r * PTW;
            int gy = min(ty0 + r, HH - 1);
            int gx = min(tx0 + col, WW - 1);
            const float* p = xb + ((size_t)(cc0 + 2 * cpair) * (HH * WW)) + gy * WW + gx;
            va[it] = p[0];
            vb[it] = p[HH * WW];
        }
    };
    auto commit = [&](int s, const float* va, const float* vb, int bufbase) {
        int tb, tx0, ty0; tile_of(s, tb, tx0, ty0);
        #pragma unroll
        for (int it = 0; it < CHITER; ++it) {
            int i  = tid + it * 256;
            int ii = (i < CHITEM) ? i : (CHITEM - 1);
            int cpair = ii / NCELLC;
            int cell  = ii - cpair * NCELLC;
            int r   = cell / PTW;
            int col = cell - r * PTW;
            bool inb = (ty0 + r < HH) && (tx0 + col < WW);
            float v0 = inb ? va[it] : 0.0f;
            float v1 = inb ? vb[it] : 0.0f;
            __hip_bfloat162 h2 = __float22bfloat162_rn(make_float2(v0, v1));
            unsigned int u; __builtin_memcpy(&u, &h2, 4);
            int lin = cell * 64 + cpair * 4;
            if (i < CHITEM)
                *(unsigned int*)(smem + bufbase + SWZ(lin)) = u;
        }
    };

    const float bias0 = offset_b[lr];
    const float bias1 = (lr < 2) ? offset_b[16 + lr] : 0.0f;
    f32x4 accC[2][2];
    f32x4 accY[2];
    auto reset_acc = [&]() {
        #pragma unroll
        for (int mi = 0; mi < 2; ++mi) {
            #pragma unroll
            for (int reg = 0; reg < 4; ++reg) { accC[mi][0][reg] = bias0; accC[mi][1][reg] = bias1; }
            accY[mi] = (f32x4){0.f, 0.f, 0.f, 0.f};
        }
    };
    reset_acc();

    const int o1 = (16 + lr > 17) ? 17 : 16 + lr;

    auto wrow = [&](int row, int cc0) -> bf16x8 {
        unsigned int byte = (unsigned)(row * 128 + (cc0 + lk * 8) * 2) ^ (((unsigned)(row & 7)) << 4);
        return *(const bf16x8*)(smem + LDS_W + byte);
    };
    auto mfma_chunk = [&](int bufbase, int cc0) {
        unsigned int byY = (unsigned)(lr * 128 + (cc0 + lk * 8) * 2) ^ (((unsigned)(lr & 7)) << 4);
        bf16x8 bY = *(const bf16x8*)(smem + LDS_W + 20736 + byY);
        #pragma unroll
        for (int tap = 0; tap < 9; ++tap) {
            const int kh = tap / 3, kw = tap % 3;
            bf16x8 b0 = wrow(tap * 18 + lr, cc0);
            bf16x8 b1 = wrow(tap * 18 + o1, cc0);
            #pragma unroll
            for (int mi = 0; mi < 2; ++mi) {
                int cell = (2 * w + mi + kh) * PTW + (lr + kw);
                bf16x8 a = *(const bf16x8*)(smem + bufbase + SWZ(cell * 64 + lk * 16));
                accC[mi][0] = __builtin_amdgcn_mfma_f32_16x16x32_bf16(a, b0, accC[mi][0], 0, 0, 0);
                accC[mi][1] = __builtin_amdgcn_mfma_f32_16x16x32_bf16(a, b1, accC[mi][1], 0, 0, 0);
                if (tap == 0)
                    accY[mi] = __builtin_amdgcn_mfma_f32_16x16x32_bf16(a, bY, accY[mi], 0, 0, 0);
            }
        }
    };
    auto store_tile = [&](int s) {
        int tb, tx0, ty0; tile_of(s, tb, tx0, ty0);
        #pragma unroll
        for (int mi = 0; mi < 2; ++mi) {
            int ho = ty0 + 2 * w + mi;
            #pragma unroll
            for (int nt = 0; nt < 2; ++nt) {
                int o = nt * 16 + lr;
                if (o < NOFF && ho < HO) {
                    float* dst = off + ((size_t)tb * NOFF + o) * NPIX + (size_t)ho * WO;
                    #pragma unroll
                    for (int reg = 0; reg < 4; ++reg) {
                        int wo = tx0 + lk * 4 + reg;
                        if (wo < WO) dst[wo] = accC[mi][nt][reg];
                    }
                }
            }
            if (lr < KK) {
                float* dst = Y + ((size_t)tb * KK + lr) * (HH * WW) + (size_t)(ty0 + 2 * w + mi) * WW + tx0;
                #pragma unroll
                for (int reg = 0; reg < 4; ++reg)
                    dst[lk * 4 + reg] = accY[mi][reg];
            }
        }
    };

    issue(0, vaA, vbA);
    issue(1, vaB, vbB);
    commit(0, vaA, vbA, LDS_B0);
    __syncthreads();

    #pragma unroll
    for (int s = 0; s < NSTEP; ++s) {
        float* iva = (s & 1) ? vaB : vaA;
        float* ivb = (s & 1) ? vbB : vbA;
        if (s + 2 < NSTEP) issue(s + 2, iva, ivb);

        mfma_chunk((s & 1) ? LDS_B1 : LDS_B0, (s & 1) * 32);

        if (s + 1 < NSTEP) {
            const float* cva = ((s + 1) & 1) ? vaB : vaA;
            const float* cvb = ((s + 1) & 1) ? vbB : vbA;
            commit(s + 1, cva, cvb, ((s + 1) & 1) ? LDS_B1 : LDS_B0);
        }
        if (s & 1) {
            store_tile(s);
            reset_acc();
        }
        __syncthreads();
    }
}

// ================= kernel G: bilinear gather on collapsed planes =================
__global__ __launch_bounds__(256) void gather_kernel(
    const float* __restrict__ off,
    const float* __restrict__ Y,
    const float* __restrict__ deform_b,
    float* __restrict__ out)
{
    int p2 = blockIdx.x * 256 + threadIdx.x;
    if (p2 >= NPIX) return;
    int b = blockIdx.y;
    int ho = p2 / WO;
    int wo = p2 - ho * WO;

    const float* offb = off + (size_t)b * NOFF * NPIX;
    const float* Yb   = Y + (size_t)b * KK * (HH * WW);

    float acc = deform_b[0];

    #pragma unroll
    for (int k = 0; k < KK; ++k) {
        const int kh = k / 3, kw = k % 3;
        float dy = offb[(size_t)(2 * k) * NPIX + p2];
        float dx = offb[(size_t)(2 * k + 1) * NPIX + p2];
        float py = (float)(ho + kh) + dy;
        float px = (float)(wo + kw) + dx;
        float y0f = floorf(py), x0f = floorf(px);
        float ly = py - y0f, lx = px - x0f;
        int yi0 = (int)y0f, xi0 = (int)x0f;
        int yi1 = yi0 + 1, xi1 = xi0 + 1;

        float w00 = (1.0f - ly) * (1.0f - lx);
        float w01 = (1.0f - ly) * lx;
        float w10 = ly * (1.0f - lx);
        float w11 = ly * lx;
        if (!(yi0 >= 0 && yi0 < HH && xi0 >= 0 && xi0 < WW)) w00 = 0.0f;
        if (!(yi0 >= 0 && yi0 < HH && xi1 >= 0 && xi1 < WW)) w01 = 0.0f;
        if (!(yi1 >= 0 && yi1 < HH && xi0 >= 0 && xi0 < WW)) w10 = 0.0f;
        if (!(yi1 >= 0 && yi1 < HH && xi1 >= 0 && xi1 < WW)) w11 = 0.0f;

        int y0c = min(max(yi0, 0), HH - 1);
        int y1c = min(max(yi1, 0), HH - 1);
        int x0c = min(max(xi0, 0), WW - 1);
        int x1c = min(max(xi1, 0), WW - 1);

        const float* Yk = Yb + (size_t)k * (HH * WW);
        acc += w00 * Yk[y0c * WW + x0c] + w01 * Yk[y0c * WW + x1c]
             + w10 * Yk[y1c * WW + x0c] + w11 * Yk[y1c * WW + x1c];
    }

    out[(size_t)b * NPIX + p2] = acc;
}

// ================= fallback: fused kernel (used if ws too small) =================
#define TS 16
#define S  2
#define PT 22
#define NCELL (PT*PT)
#define FOFF_SX   0
#define FOFF_BC   30976
#define FOFF_DW   56896
#define FSMEM_SZ  59200
#define FOFF_SOFF 0
#define FOFF_SY   18504

__global__ __launch_bounds__(256) void deform_fused_fallback(
    const float* __restrict__ x,
    const float* __restrict__ offset_w,
    const float* __restrict__ offset_b,
    const float* __restrict__ deform_w,
    const float* __restrict__ deform_b,
    float* __restrict__ out)
{
    __shared__ __align__(16) unsigned char smem[FSMEM_SZ];

    const int tid = threadIdx.x;
    const int x0 = blockIdx.x * TS;
    const int y0 = blockIdx.y * TS;
    const int b  = blockIdx.z;
    const float* xb = x + (size_t)b * CC * HH * WW;

    for (int i = tid; i < 9 * 20 * 64; i += 256) {
        int tap = i / 1280;
        int rem = i - tap * 1280;
        int o   = rem >> 6;
        int c   = rem & 63;
        float v = (o < NOFF) ? offset_w[((size_t)o * CC + c) * KK + tap] : 0.0f;
        *(unsigned short*)(smem + FOFF_BC + ((size_t)(tap * 20 + o) * 144 + c * 2)) = f2bf(v);
    }
    for (int i = tid; i < 16 * 64; i += 256) {
        int tap = i >> 6;
        int c   = i & 63;
        float v = (tap < KK) ? deform_w[(size_t)c * KK + tap] : 0.0f;
        *(unsigned short*)(smem + FOFF_DW + (size_t)tap * 144 + c * 2) = f2bf(v);
    }

    auto stage_x = [&](int cc0) {
        for (int i = tid; i < 16 * 512; i += 256) {
            int cpair = i >> 9;
            int cell  = i & 511;
            if (cell >= NCELL) continue;
            int r   = cell / PT;
            int col = cell - r * PT;
            int gy = y0 - S + r;
            int gx = x0 - S + col;
            float v0 = 0.0f, v1 = 0.0f;
            if (gy >= 0 && gy < HH && gx >= 0 && gx < WW) {
                const float* p = xb + (size_t)(cc0 + 2 * cpair) * (HH * WW) + gy * WW + gx;
                v0 = p[0];
                v1 = p[HH * WW];
            }
            __hip_bfloat162 h2 = __float22bfloat162_rn(make_float2(v0, v1));
            unsigned int u; __builtin_memcpy(&u, &h2, 4);
            int lin = cell * 64 + cpair * 4;
            *(unsigned int*)(smem + FOFF_SX + SWZ(lin)) = u;
        }
    };

    stage_x(0);
    __syncthreads();

    const int w  = tid >> 6;
    const int l  = tid & 63;
    const int lr = l & 15;
    const int lk = l >> 4;

    float bias0 = offset_b[lr];
    float bias1 = (lr < 2) ? offset_b[16 + lr] : 0.0f;
    f32x4 accC[4][2];
    #pragma unroll
    for (int mi = 0; mi < 4; ++mi)
        #pragma unroll
        for (int reg = 0; reg < 4; ++reg) { accC[mi][0][reg] = bias0; accC[mi][1][reg] = bias1; }
    f32x4 accY[8];
    #pragma unroll
    for (int yi = 0; yi < 8; ++yi) accY[yi] = (f32x4){0.f, 0.f, 0.f, 0.f};

    #pragma unroll
    for (int half = 0; half < 2; ++half) {
        const int cc0 = half * 32;
        const int koff = lk * 16;

        #pragma unroll
        for (int tap = 0; tap < 9; ++tap) {
            const int kh = tap / 3, kw = tap % 3;
            bf16x8 b0 = *(const bf16x8*)(smem + FOFF_BC + (size_t)(tap * 20 + lr) * 144 + (cc0 + lk * 8) * 2);
            int o1f = 16 + lr; if (o1f > 19) o1f = 19;
            bf16x8 b1 = *(const bf16x8*)(smem + FOFF_BC + (size_t)(tap * 20 + o1f) * 144 + (cc0 + lk * 8) * 2);
            #pragma unroll
            for (int mi = 0; mi < 4; ++mi) {
                int row  = 4 * w + mi;
                int cell = (row + kh + S) * PT + (lr + kw + S);
                bf16x8 a = *(const bf16x8*)(smem + FOFF_SX + SWZ(cell * 64 + koff));
                accC[mi][0] = __builtin_amdgcn_mfma_f32_16x16x32_bf16(a, b0, accC[mi][0], 0, 0, 0);
                accC[mi][1] = __builtin_amdgcn_mfma_f32_16x16x32_bf16(a, b1, accC[mi][1], 0, 0, 0);
            }
        }

        bf16x8 bY = *(const bf16x8*)(smem + FOFF_DW + (size_t)lr * 144 + (cc0 + lk * 8) * 2);
        #pragma unroll
        for (int yi = 0; yi < 8; ++yi) {
            int tile = 8 * w + yi;
            if (tile < 31) {
                int cell = tile * 16 + lr; if (cell > NCELL - 1) cell = NCELL - 1;
                bf16x8 a = *(const bf16x8*)(smem + FOFF_SX + SWZ(cell * 64 + koff));
                accY[yi] = __builtin_amdgcn_mfma_f32_16x16x32_bf16(a, bY, accY[yi], 0, 0, 0);
            }
        }

        if (half == 0) {
            __syncthreads();
            stage_x(32);
            __syncthreads();
        }
    }

    __syncthreads();

    float* s_off = (float*)(smem + FOFF_SOFF);
    float* s_Y   = (float*)(smem + FOFF_SY);
    #pragma unroll
    for (int mi = 0; mi < 4; ++mi) {
        #pragma unroll
        for (int nt = 0; nt < 2; ++nt) {
            int o = nt * 16 + lr;
            if (o < NOFF) {
                int pbase = (4 * w + mi) * 16 + lk * 4;
                #pragma unroll
                for (int reg = 0; reg < 4; ++reg)
                    s_off[o * 257 + pbase + reg] = accC[mi][nt][reg];
            }
        }
    }
    #pragma unroll
    for (int yi = 0; yi < 8; ++yi) {
        int tile = 8 * w + yi;
        if (tile < 31 && lr < KK) {
            #pragma unroll
            for (int reg = 0; reg < 4; ++reg) {
                int cell = tile * 16 + lk * 4 + reg;
                if (cell < NCELL) s_Y[lr * 485 + cell] = accY[yi][reg];
            }
        }
    }
    __syncthreads();

    const int ty = tid >> 4, tx = tid & 15;
    const int ho = y0 + ty, wo = x0 + tx;
    if (ho >= HO || wo >= WO) return;

    float acc = deform_b[0];

    #pragma unroll
    for (int k = 0; k < KK; ++k) {
        const int kh = k / 3, kw = k % 3;
        float dy = s_off[(2 * k) * 257 + tid];
        float dx = s_off[(2 * k + 1) * 257 + tid];
        float py = (float)(ho + kh) + dy;
        float px = (float)(wo + kw) + dx;
        float y0f = floorf(py), x0f = floorf(px);
        float ly = py - y0f, lx = px - x0f;
        int yi0 = (int)y0f, xi0 = (int)x0f;
        int ry = yi0 - (y0 - S);
        int rx = xi0 - (x0 - S);
        float w00 = (1.0f - ly) * (1.0f - lx);
        float w01 = (1.0f - ly) * lx;
        float w10 = ly * (1.0f - lx);
        float w11 = ly * lx;
        float g;
        if ((unsigned)ry <= (unsigned)(PT - 2) && (unsigned)rx <= (unsigned)(PT - 2)) {
            const float* tp = s_Y + k * 485;
            int id = ry * PT + rx;
            g = w00 * tp[id]      + w01 * tp[id + 1]
              + w10 * tp[id + PT] + w11 * tp[id + PT + 1];
        } else {
            int yi1 = yi0 + 1, xi1 = xi0 + 1;
            float m00 = (yi0 >= 0 && yi0 < HH && xi0 >= 0 && xi0 < WW) ? w00 : 0.0f;
            float m01 = (yi0 >= 0 && yi0 < HH && xi1 >= 0 && xi1 < WW) ? w01 : 0.0f;
            float m10 = (yi1 >= 0 && yi1 < HH && xi0 >= 0 && xi0 < WW) ? w10 : 0.0f;
            float m11 = (yi1 >= 0 && yi1 < HH && xi1 >= 0 && xi1 < WW) ? w11 : 0.0f;
            int y0cl = min(max(yi0, 0), HH - 1), y1cl = min(max(yi1, 0), HH - 1);
            int x0cl = min(max(xi0, 0), WW - 1), x1cl = min(max(xi1, 0), WW - 1);
            g = 0.0f;
            for (int c = 0; c < CC; ++c) {
                const float* xc = xb + (size_t)c * (HH * WW);
                float gc = m00 * xc[y0cl * WW + x0cl] + m01 * xc[y0cl * WW + x1cl]
                         + m10 * xc[y1cl * WW + x0cl] + m11 * xc[y1cl * WW + x1cl];
                gc *= deform_w[(size_t)c * KK + k];
                g += gc;
            }
        }
        acc += g;
    }

    out[(size_t)b * (HO * WO) + ho * WO + wo] = acc;
}

extern "C" void kernel_launch(void* const* d_in, const int* in_sizes, int n_in,
                              void* d_out, int out_size, void* d_ws, size_t ws_size,
                              hipStream_t stream) {
    const float* x        = (const float*)d_in[0];
    const float* offset_w = (const float*)d_in[1];
    const float* offset_b = (const float*)d_in[2];
    const float* deform_w = (const float*)d_in[3];
    const float* deform_b = (const float*)d_in[4];
    float* out = (float*)d_out;

    if (ws_size >= (size_t)WS_NEED2) {
        unsigned char* ws = (unsigned char*)d_ws;
        float* off = (float*)(ws + WS_OFF);
        float* Y   = (float*)(ws + WS_Y);
        unsigned short* xT = (unsigned short*)(ws + WS_XT);

        hipLaunchKernelGGL(transpose_kernel, dim3(4, 256, BB), dim3(256), 0, stream,
                           x, xT, offset_w, deform_w, ws);
        hipLaunchKernelGGL(convY_direct, dim3(512), dim3(1024), 0, stream,
                           xT, offset_b, ws, off, Y);
        hipLaunchKernelGGL(gather_kernel, dim3((NPIX + 255) / 256, BB), dim3(256), 0, stream,
                           off, Y, deform_b, out);
    } else if (ws_size >= (size_t)WS_NEED) {
        unsigned char* ws = (unsigned char*)d_ws;
        float* off = (float*)(ws + WS_OFF);
        float* Y   = (float*)(ws + WS_Y);

        hipLaunchKernelGGL(repack_kernel, dim3(10), dim3(256), 0, stream,
                           offset_w, deform_w, ws);
        hipLaunchKernelGGL(convY_kernel, dim3(512), dim3(256), 0, stream,
                           x, offset_b, ws, off, Y);
        hipLaunchKernelGGL(gather_kernel, dim3((NPIX + 255) / 256, BB), dim3(256), 0, stream,
                           off, Y, deform_b, out);
    } else {
        dim3 block(256);
        dim3 grid((WO + TS - 1) / TS, (HO + TS - 1) / TS, BB);
        hipLaunchKernelGGL(deform_fused_fallback, grid, block, 0, stream,
                           x, offset_w, offset_b, deform_w, deform_b, out);
    }
}

// Round 12
// 56.827 us; speedup vs baseline: 1.2820x; 1.2820x over previous
//
#include <hip/hip_runtime.h>
#include <hip/hip_bf16.h>

#define BB 4
#define CC 64
#define HH 256
#define WW 256
#define KK 9
#define NOFF 18
#define HO 254
#define WO 254
#define NPIX (HO*WO)           // 64516

// ---------------- workspace layout ----------------
#define WS_W    0
#define WS_OFF  32768
#define WS_Y    (WS_OFF + BB*NOFF*NPIX*4)           // 18,613,376
#define WS_NEED (WS_Y + BB*KK*HH*WW*4)              // 28,050,560  (mid path)
#define WS_XT_F 32768
#define WS_NEED_F (WS_XT_F + (size_t)BB*HH*WW*CC*2) // 33,587,200  (fast path)

#define SWZ(lin) ((lin) ^ ((((lin) >> 7) & 7) << 4))

typedef __attribute__((ext_vector_type(8))) short bf16x8;
typedef __attribute__((ext_vector_type(4))) float f32x4;

static __device__ __forceinline__ unsigned short f2bf(float v) {
    __hip_bfloat16 h = __float2bfloat16(v);
    union { __hip_bfloat16 b; unsigned short u; } cv; cv.b = h; return cv.u;
}
static __device__ __forceinline__ float bf2f(unsigned short u) {
    unsigned int w = ((unsigned int)u) << 16;
    float f; __builtin_memcpy(&f, &w, 4); return f;
}

static __device__ __forceinline__ void repack_piece(
    int tap, int tid, int nthr,
    const float* __restrict__ offset_w,
    const float* __restrict__ deform_w,
    unsigned char* __restrict__ ws)
{
    if (tap < 9) {
        for (int i = tid; i < 18 * 64; i += nthr) {
            int o = i >> 6;
            int c = i & 63;
            int row = tap * 18 + o;
            unsigned int byte = (unsigned)(row * 128 + c * 2) ^ (((unsigned)(row & 7)) << 4);
            *(unsigned short*)(ws + WS_W + byte) = f2bf(offset_w[((size_t)o * CC + c) * KK + tap]);
        }
    } else {
        for (int i = tid; i < 16 * 64; i += nthr) {
            int t = i >> 6;
            int c = i & 63;
            float v = (t < KK) ? deform_w[(size_t)c * KK + t] : 0.0f;
            unsigned int byte = (unsigned)(t * 128 + c * 2) ^ (((unsigned)(t & 7)) << 4);
            *(unsigned short*)(ws + WS_W + 20736 + byte) = f2bf(v);
        }
    }
}

// ================= kernel W: standalone repack (mid path only) =================
__global__ __launch_bounds__(256) void repack_kernel(
    const float* __restrict__ offset_w,
    const float* __restrict__ deform_w,
    unsigned char* __restrict__ ws)
{
    repack_piece(blockIdx.x, threadIdx.x, 256, offset_w, deform_w, ws);
}

// ========== kernel P: x NCHW f32 -> xT NHWC bf16 (+ fused weight repack) ==========
__global__ __launch_bounds__(256) void transpose_kernel(
    const float* __restrict__ x,
    unsigned short* __restrict__ xT,
    const float* __restrict__ offset_w,
    const float* __restrict__ deform_w,
    unsigned char* __restrict__ ws)
{
    __shared__ float s[64][65];
    const int tid = threadIdx.x;
    const int w0 = blockIdx.x * 64;
    const int h  = blockIdx.y;
    const int b  = blockIdx.z;

    if (b == 0 && blockIdx.x == 0 && h < 10)
        repack_piece(h, tid, 256, offset_w, deform_w, ws);

    #pragma unroll
    for (int it = 0; it < 4; ++it) {
        int i  = tid + it * 256;
        int c  = i >> 4;
        int p4 = (i & 15) << 2;
        float4 v = *(const float4*)(x + (((size_t)b * CC + c) * HH + h) * WW + w0 + p4);
        s[c][p4 + 0] = v.x; s[c][p4 + 1] = v.y; s[c][p4 + 2] = v.z; s[c][p4 + 3] = v.w;
    }
    __syncthreads();
    #pragma unroll
    for (int it = 0; it < 2; ++it) {
        int j  = tid + it * 256;
        int px = j >> 3;
        int g  = j & 7;
        unsigned int u[4];
        #pragma unroll
        for (int q = 0; q < 4; ++q) {
            __hip_bfloat162 h2 = __float22bfloat162_rn(
                make_float2(s[g * 8 + 2 * q][px], s[g * 8 + 2 * q + 1][px]));
            __builtin_memcpy(&u[q], &h2, 4);
        }
        unsigned short* dst = xT + (((size_t)b * HH + h) * WW + w0 + px) * 64 + g * 8;
        *(uint4*)dst = make_uint4(u[0], u[1], u[2], u[3]);
    }
}

// ====== kernel F: fused conv + Y-ext + in-LDS gather (fast path, 1024 blocks) ======
// 16x16 output tile per block (4 waves). Y computed on 22x22 slack patch in-block.
#define PTF 22
#define NCF 484     // 22*22
#define LDS_SOFF 0      // f32 [18][257] = 18504 B  (phase 2, aliases weights)
#define LDS_SY   18504  // f32 [9][485]  = 17460 B
#define SMEM_F   35968

__global__ __launch_bounds__(256) void conv_gather_fused(
    const unsigned short* __restrict__ xT,
    const float* __restrict__ offset_b,
    const unsigned char* __restrict__ ws_w,
    const float* __restrict__ deform_w,
    const float* __restrict__ deform_b,
    float* __restrict__ out)
{
    __shared__ __align__(16) unsigned char smem[SMEM_F];
    const int tid = threadIdx.x;

    {   // stage swizzled weights (22784 B)
        const uint4* src = (const uint4*)ws_w;
        uint4* dst = (uint4*)smem;
        for (int i = tid; i < 1424; i += 256) dst[i] = src[i];
    }
    __syncthreads();

    const int wv = tid >> 6;
    const int l  = tid & 63;
    const int lr = l & 15;
    const int lk = l >> 4;

    const int x0 = blockIdx.x * 16;
    const int y0 = blockIdx.y * 16;
    const int b  = blockIdx.z;
    const unsigned char* xb = (const unsigned char*)(xT + (size_t)b * HH * WW * 64);

    const int o1 = (16 + lr > 17) ? 17 : 16 + lr;
    const float bias0 = offset_b[lr];
    const float bias1 = (lr < 2) ? offset_b[16 + lr] : 0.0f;

    f32x4 accC[4][2];
    f32x4 accY[8];
    #pragma unroll
    for (int mi = 0; mi < 4; ++mi)
        #pragma unroll
        for (int reg = 0; reg < 4; ++reg) { accC[mi][0][reg] = bias0; accC[mi][1][reg] = bias1; }
    #pragma unroll
    for (int j = 0; j < 8; ++j) accY[j] = (f32x4){0.f, 0.f, 0.f, 0.f};

    auto ldw = [&](int row, int cbyte) -> bf16x8 {
        unsigned int byte = (unsigned)(row * 128 + cbyte) ^ (((unsigned)(row & 7)) << 4);
        return *(const bf16x8*)(smem + byte);
    };

    // ---------------- phase 1: MFMA (A-frags direct from xT) ----------------
    #pragma unroll
    for (int ch = 0; ch < 2; ++ch) {
        const int cbyte = ch * 64 + lk * 16;
        // offset conv: wave wv owns image rows y0+4*wv+mi (mi 0..3)
        #pragma unroll
        for (int kw = 0; kw < 3; ++kw) {
            const int gx = min(x0 + lr + kw, WW - 1);
            bf16x8 a[6];
            #pragma unroll
            for (int rr = 0; rr < 6; ++rr) {
                const int gy = min(y0 + 4 * wv + rr, HH - 1);
                a[rr] = *(const bf16x8*)(xb + (size_t)(gy * WW + gx) * 128 + cbyte);
            }
            #pragma unroll
            for (int kh = 0; kh < 3; ++kh) {
                const int tap = kh * 3 + kw;
                bf16x8 b0 = ldw(tap * 18 + lr, cbyte);
                bf16x8 b1 = ldw(tap * 18 + o1, cbyte);
                #pragma unroll
                for (int mi = 0; mi < 4; ++mi) {
                    accC[mi][0] = __builtin_amdgcn_mfma_f32_16x16x32_bf16(a[mi + kh], b0, accC[mi][0], 0, 0, 0);
                    accC[mi][1] = __builtin_amdgcn_mfma_f32_16x16x32_bf16(a[mi + kh], b1, accC[mi][1], 0, 0, 0);
                }
            }
        }
        // Y-ext: 484 cells over 22x22 patch, 31 M-tiles, wave handles t = wv+4j
        {
            unsigned int byY = (unsigned)(lr * 128 + cbyte) ^ (((unsigned)(lr & 7)) << 4);
            bf16x8 bY = *(const bf16x8*)(smem + 20736 + byY);
            #pragma unroll
            for (int j = 0; j < 8; ++j) {
                const int t = wv + 4 * j;
                if (t < 31) {
                    int cell = t * 16 + lr; if (cell > NCF - 1) cell = NCF - 1;
                    int r = cell / PTF, col = cell - r * PTF;
                    int gy = min(max(y0 - 2 + r, 0), HH - 1);
                    int gx = min(max(x0 - 2 + col, 0), WW - 1);
                    bf16x8 a = *(const bf16x8*)(xb + (size_t)(gy * WW + gx) * 128 + cbyte);
                    accY[j] = __builtin_amdgcn_mfma_f32_16x16x32_bf16(a, bY, accY[j], 0, 0, 0);
                }
            }
        }
    }

    __syncthreads();   // all weight reads done; arena can be re-used

    // ---------------- phase 2: redistribute to LDS ----------------
    float* s_off = (float*)(smem + LDS_SOFF);   // [18][257]
    float* s_Y   = (float*)(smem + LDS_SY);     // [9][485]
    #pragma unroll
    for (int mi = 0; mi < 4; ++mi) {
        #pragma unroll
        for (int nt = 0; nt < 2; ++nt) {
            const int o = nt * 16 + lr;
            if (o < NOFF) {
                const int pbase = (4 * wv + mi) * 16 + lk * 4;
                #pragma unroll
                for (int reg = 0; reg < 4; ++reg)
                    s_off[o * 257 + pbase + reg] = accC[mi][nt][reg];
            }
        }
    }
    #pragma unroll
    for (int j = 0; j < 8; ++j) {
        const int t = wv + 4 * j;
        if (t < 31 && lr < KK) {
            #pragma unroll
            for (int reg = 0; reg < 4; ++reg) {
                const int cell = t * 16 + lk * 4 + reg;
                if (cell < NCF) {
                    int r = cell / PTF, col = cell - r * PTF;
                    int gy = y0 - 2 + r, gx = x0 - 2 + col;
                    bool inimg = (gy >= 0 && gy < HH && gx >= 0 && gx < WW);
                    s_Y[lr * 485 + cell] = inimg ? accY[j][reg] : 0.0f;
                }
            }
        }
    }
    __syncthreads();

    // ---------------- phase 3: in-LDS bilinear gather ----------------
    const int ty = tid >> 4, tx = tid & 15;
    const int ho = y0 + ty, wo = x0 + tx;
    if (ho >= HO || wo >= WO) return;

    float acc = deform_b[0];

    #pragma unroll
    for (int k = 0; k < KK; ++k) {
        const int kh = k / 3, kw = k % 3;
        float dy = s_off[(2 * k) * 257 + tid];
        float dx = s_off[(2 * k + 1) * 257 + tid];
        float py = (float)(ho + kh) + dy;
        float px = (float)(wo + kw) + dx;
        float y0f = floorf(py), x0f = floorf(px);
        float ly = py - y0f, lx = px - x0f;
        int yi0 = (int)y0f, xi0 = (int)x0f;
        int ry = yi0 - (y0 - 2);
        int rx = xi0 - (x0 - 2);
        float w00 = (1.0f - ly) * (1.0f - lx);
        float w01 = (1.0f - ly) * lx;
        float w10 = ly * (1.0f - lx);
        float w11 = ly * lx;
        float g;
        if ((unsigned)ry <= (unsigned)(PTF - 2) && (unsigned)rx <= (unsigned)(PTF - 2)) {
            // fast path: all 4 corners inside slack patch; out-of-image cells are 0
            const float* tp = s_Y + k * 485;
            const int id = ry * PTF + rx;
            g = w00 * tp[id]       + w01 * tp[id + 1]
              + w10 * tp[id + PTF] + w11 * tp[id + PTF + 1];
        } else {
            // rare fallback: exact bilinear over channels from xT
            int yi1 = yi0 + 1, xi1 = xi0 + 1;
            float m00 = (yi0 >= 0 && yi0 < HH && xi0 >= 0 && xi0 < WW) ? w00 : 0.0f;
            float m01 = (yi0 >= 0 && yi0 < HH && xi1 >= 0 && xi1 < WW) ? w01 : 0.0f;
            float m10 = (yi1 >= 0 && yi1 < HH && xi0 >= 0 && xi0 < WW) ? w10 : 0.0f;
            float m11 = (yi1 >= 0 && yi1 < HH && xi1 >= 0 && xi1 < WW) ? w11 : 0.0f;
            int y0c = min(max(yi0, 0), HH - 1), y1c = min(max(yi1, 0), HH - 1);
            int x0c = min(max(xi0, 0), WW - 1), x1c = min(max(xi1, 0), WW - 1);
            const unsigned short* p00 = (const unsigned short*)(xb + (size_t)(y0c * WW + x0c) * 128);
            const unsigned short* p01 = (const unsigned short*)(xb + (size_t)(y0c * WW + x1c) * 128);
            const unsigned short* p10 = (const unsigned short*)(xb + (size_t)(y1c * WW + x0c) * 128);
            const unsigned short* p11 = (const unsigned short*)(xb + (size_t)(y1c * WW + x1c) * 128);
            g = 0.0f;
            for (int c = 0; c < CC; ++c) {
                float gc = m00 * bf2f(p00[c]) + m01 * bf2f(p01[c])
                         + m10 * bf2f(p10[c]) + m11 * bf2f(p11[c]);
                g = fmaf(gc, deform_w[(size_t)c * KK + k], g);
            }
        }
        acc += g;
    }

    out[(size_t)b * NPIX + ho * WO + wo] = acc;
}

// ================= kernel C (mid path): persistent pipelined conv + Y ============
#define TSH 8
#define TSW 16
#define PTH 10
#define PTW 18
#define NCELLC (PTH*PTW)
#define CHITEM (16*NCELLC)
#define CHITER 12
#define LDS_W   0
#define LDS_B0  22784
#define LDS_B1  34304
#define SMEM_C  45824
#define NT      4
#define NSTEP   (NT*2)

__global__ __launch_bounds__(256) void convY_kernel(
    const float* __restrict__ x,
    const float* __restrict__ offset_b,
    const unsigned char* __restrict__ ws_w,
    float* __restrict__ off,
    float* __restrict__ Y)
{
    __shared__ __align__(16) unsigned char smem[SMEM_C];

    const int tid = threadIdx.x;
    const int bid = blockIdx.x;

    {
        const uint4* src = (const uint4*)ws_w;
        uint4* dst = (uint4*)(smem + LDS_W);
        for (int i = tid; i < 1424; i += 256) dst[i] = src[i];
    }

    const int w  = tid >> 6;
    const int l  = tid & 63;
    const int lr = l & 15;
    const int lk = l >> 4;

    auto tile_of = [&](int s, int& tb, int& tx0, int& ty0) {
        int t4 = bid * NT + (s >> 1);
        tb  = t4 >> 9;
        int rem = t4 & 511;
        ty0 = (rem >> 4) * TSH;
        tx0 = (rem & 15) * TSW;
    };

    float vaA[CHITER], vbA[CHITER], vaB[CHITER], vbB[CHITER];

    auto issue = [&](int s, float* va, float* vb) {
        int tb, tx0, ty0; tile_of(s, tb, tx0, ty0);
        const int cc0 = (s & 1) * 32;
        const float* xb = x + (size_t)tb * CC * HH * WW;
        #pragma unroll
        for (int it = 0; it < CHITER; ++it) {
            int i  = tid + it * 256;
            int ii = (i < CHITEM) ? i : (CHITEM - 1);
            int cpair = ii / NCELLC;
            int cell  = ii - cpair * NCELLC;
            int r   = cell / PTW;
            int col = cell - r * PTW;
            int gy = min(ty0 + r, HH - 1);
            int gx = min(tx0 + col, WW - 1);
            const float* p = xb + ((size_t)(cc0 + 2 * cpair) * (HH * WW)) + gy * WW + gx;
            va[it] = p[0];
            vb[it] = p[HH * WW];
        }
    };
    auto commit = [&](int s, const float* va, const float* vb, int bufbase) {
        int tb, tx0, ty0; tile_of(s, tb, tx0, ty0);
        #pragma unroll
        for (int it = 0; it < CHITER; ++it) {
            int i  = tid + it * 256;
            int ii = (i < CHITEM) ? i : (CHITEM - 1);
            int cpair = ii / NCELLC;
            int cell  = ii - cpair * NCELLC;
            int r   = cell / PTW;
            int col = cell - r * PTW;
            bool inb = (ty0 + r < HH) && (tx0 + col < WW);
            float v0 = inb ? va[it] : 0.0f;
            float v1 = inb ? vb[it] : 0.0f;
            __hip_bfloat162 h2 = __float22bfloat162_rn(make_float2(v0, v1));
            unsigned int u; __builtin_memcpy(&u, &h2, 4);
            int lin = cell * 64 + cpair * 4;
            if (i < CHITEM)
                *(unsigned int*)(smem + bufbase + SWZ(lin)) = u;
        }
    };

    const float bias0 = offset_b[lr];
    const float bias1 = (lr < 2) ? offset_b[16 + lr] : 0.0f;
    f32x4 accC[2][2];
    f32x4 accY[2];
    auto reset_acc = [&]() {
        #pragma unroll
        for (int mi = 0; mi < 2; ++mi) {
            #pragma unroll
            for (int reg = 0; reg < 4; ++reg) { accC[mi][0][reg] = bias0; accC[mi][1][reg] = bias1; }
            accY[mi] = (f32x4){0.f, 0.f, 0.f, 0.f};
        }
    };
    reset_acc();

    const int o1 = (16 + lr > 17) ? 17 : 16 + lr;

    auto wrow = [&](int row, int cc0) -> bf16x8 {
        unsigned int byte = (unsigned)(row * 128 + (cc0 + lk * 8) * 2) ^ (((unsigned)(row & 7)) << 4);
        return *(const bf16x8*)(smem + LDS_W + byte);
    };
    auto mfma_chunk = [&](int bufbase, int cc0) {
        unsigned int byY = (unsigned)(lr * 128 + (cc0 + lk * 8) * 2) ^ (((unsigned)(lr & 7)) << 4);
        bf16x8 bY = *(const bf16x8*)(smem + LDS_W + 20736 + byY);
        #pragma unroll
        for (int tap = 0; tap < 9; ++tap) {
            const int kh = tap / 3, kw = tap % 3;
            bf16x8 b0 = wrow(tap * 18 + lr, cc0);
            bf16x8 b1 = wrow(tap * 18 + o1, cc0);
            #pragma unroll
            for (int mi = 0; mi < 2; ++mi) {
                int cell = (2 * w + mi + kh) * PTW + (lr + kw);
                bf16x8 a = *(const bf16x8*)(smem + bufbase + SWZ(cell * 64 + lk * 16));
                accC[mi][0] = __builtin_amdgcn_mfma_f32_16x16x32_bf16(a, b0, accC[mi][0], 0, 0, 0);
                accC[mi][1] = __builtin_amdgcn_mfma_f32_16x16x32_bf16(a, b1, accC[mi][1], 0, 0, 0);
                if (tap == 0)
                    accY[mi] = __builtin_amdgcn_mfma_f32_16x16x32_bf16(a, bY, accY[mi], 0, 0, 0);
            }
        }
    };
    auto store_tile = [&](int s) {
        int tb, tx0, ty0; tile_of(s, tb, tx0, ty0);
        #pragma unroll
        for (int mi = 0; mi < 2; ++mi) {
            int ho = ty0 + 2 * w + mi;
            #pragma unroll
            for (int nt = 0; nt < 2; ++nt) {
                int o = nt * 16 + lr;
                if (o < NOFF && ho < HO) {
                    float* dst = off + ((size_t)tb * NOFF + o) * NPIX + (size_t)ho * WO;
                    #pragma unroll
                    for (int reg = 0; reg < 4; ++reg) {
                        int wo = tx0 + lk * 4 + reg;
                        if (wo < WO) dst[wo] = accC[mi][nt][reg];
                    }
                }
            }
            if (lr < KK) {
                float* dst = Y + ((size_t)tb * KK + lr) * (HH * WW) + (size_t)(ty0 + 2 * w + mi) * WW + tx0;
                #pragma unroll
                for (int reg = 0; reg < 4; ++reg)
                    dst[lk * 4 + reg] = accY[mi][reg];
            }
        }
    };

    issue(0, vaA, vbA);
    issue(1, vaB, vbB);
    commit(0, vaA, vbA, LDS_B0);
    __syncthreads();

    #pragma unroll
    for (int s = 0; s < NSTEP; ++s) {
        float* iva = (s & 1) ? vaB : vaA;
        float* ivb = (s & 1) ? vbB : vbA;
        if (s + 2 < NSTEP) issue(s + 2, iva, ivb);

        mfma_chunk((s & 1) ? LDS_B1 : LDS_B0, (s & 1) * 32);

        if (s + 1 < NSTEP) {
            const float* cva = ((s + 1) & 1) ? vaB : vaA;
            const float* cvb = ((s + 1) & 1) ? vbB : vbA;
            commit(s + 1, cva, cvb, ((s + 1) & 1) ? LDS_B1 : LDS_B0);
        }
        if (s & 1) {
            store_tile(s);
            reset_acc();
        }
        __syncthreads();
    }
}

// ================= kernel G: bilinear gather on collapsed planes (mid path) =========
__global__ __launch_bounds__(256) void gather_kernel(
    const float* __restrict__ off,
    const float* __restrict__ Y,
    const float* __restrict__ deform_b,
    float* __restrict__ out)
{
    int p2 = blockIdx.x * 256 + threadIdx.x;
    if (p2 >= NPIX) return;
    int b = blockIdx.y;
    int ho = p2 / WO;
    int wo = p2 - ho * WO;

    const float* offb = off + (size_t)b * NOFF * NPIX;
    const float* Yb   = Y + (size_t)b * KK * (HH * WW);

    float acc = deform_b[0];

    #pragma unroll
    for (int k = 0; k < KK; ++k) {
        const int kh = k / 3, kw = k % 3;
        float dy = offb[(size_t)(2 * k) * NPIX + p2];
        float dx = offb[(size_t)(2 * k + 1) * NPIX + p2];
        float py = (float)(ho + kh) + dy;
        float px = (float)(wo + kw) + dx;
        float y0f = floorf(py), x0f = floorf(px);
        float ly = py - y0f, lx = px - x0f;
        int yi0 = (int)y0f, xi0 = (int)x0f;
        int yi1 = yi0 + 1, xi1 = xi0 + 1;

        float w00 = (1.0f - ly) * (1.0f - lx);
        float w01 = (1.0f - ly) * lx;
        float w10 = ly * (1.0f - lx);
        float w11 = ly * lx;
        if (!(yi0 >= 0 && yi0 < HH && xi0 >= 0 && xi0 < WW)) w00 = 0.0f;
        if (!(yi0 >= 0 && yi0 < HH && xi1 >= 0 && xi1 < WW)) w01 = 0.0f;
        if (!(yi1 >= 0 && yi1 < HH && xi0 >= 0 && xi0 < WW)) w10 = 0.0f;
        if (!(yi1 >= 0 && yi1 < HH && xi1 >= 0 && xi1 < WW)) w11 = 0.0f;

        int y0c = min(max(yi0, 0), HH - 1);
        int y1c = min(max(yi1, 0), HH - 1);
        int x0c = min(max(xi0, 0), WW - 1);
        int x1c = min(max(xi1, 0), WW - 1);

        const float* Yk = Yb + (size_t)k * (HH * WW);
        acc += w00 * Yk[y0c * WW + x0c] + w01 * Yk[y0c * WW + x1c]
             + w10 * Yk[y1c * WW + x0c] + w11 * Yk[y1c * WW + x1c];
    }

    out[(size_t)b * NPIX + p2] = acc;
}

// ================= fallback: fused kernel (used if ws too small) =================
#define TS 16
#define S  2
#define PT 22
#define NCELL (PT*PT)
#define FOFF_SX   0
#define FOFF_BC   30976
#define FOFF_DW   56896
#define FSMEM_SZ  59200
#define FOFF_SOFF 0
#define FOFF_SY   18504

__global__ __launch_bounds__(256) void deform_fused_fallback(
    const float* __restrict__ x,
    const float* __restrict__ offset_w,
    const float* __restrict__ offset_b,
    const float* __restrict__ deform_w,
    const float* __restrict__ deform_b,
    float* __restrict__ out)
{
    __shared__ __align__(16) unsigned char smem[FSMEM_SZ];

    const int tid = threadIdx.x;
    const int x0 = blockIdx.x * TS;
    const int y0 = blockIdx.y * TS;
    const int b  = blockIdx.z;
    const float* xb = x + (size_t)b * CC * HH * WW;

    for (int i = tid; i < 9 * 20 * 64; i += 256) {
        int tap = i / 1280;
        int rem = i - tap * 1280;
        int o   = rem >> 6;
        int c   = rem & 63;
        float v = (o < NOFF) ? offset_w[((size_t)o * CC + c) * KK + tap] : 0.0f;
        *(unsigned short*)(smem + FOFF_BC + ((size_t)(tap * 20 + o) * 144 + c * 2)) = f2bf(v);
    }
    for (int i = tid; i < 16 * 64; i += 256) {
        int tap = i >> 6;
        int c   = i & 63;
        float v = (tap < KK) ? deform_w[(size_t)c * KK + tap] : 0.0f;
        *(unsigned short*)(smem + FOFF_DW + (size_t)tap * 144 + c * 2) = f2bf(v);
    }

    auto stage_x = [&](int cc0) {
        for (int i = tid; i < 16 * 512; i += 256) {
            int cpair = i >> 9;
            int cell  = i & 511;
            if (cell >= NCELL) continue;
            int r   = cell / PT;
            int col = cell - r * PT;
            int gy = y0 - S + r;
            int gx = x0 - S + col;
            float v0 = 0.0f, v1 = 0.0f;
            if (gy >= 0 && gy < HH && gx >= 0 && gx < WW) {
                const float* p = xb + (size_t)(cc0 + 2 * cpair) * (HH * WW) + gy * WW + gx;
                v0 = p[0];
                v1 = p[HH * WW];
            }
            __hip_bfloat162 h2 = __float22bfloat162_rn(make_float2(v0, v1));
            unsigned int u; __builtin_memcpy(&u, &h2, 4);
            int lin = cell * 64 + cpair * 4;
            *(unsigned int*)(smem + FOFF_SX + SWZ(lin)) = u;
        }
    };

    stage_x(0);
    __syncthreads();

    const int w  = tid >> 6;
    const int l  = tid & 63;
    const int lr = l & 15;
    const int lk = l >> 4;

    float bias0 = offset_b[lr];
    float bias1 = (lr < 2) ? offset_b[16 + lr] : 0.0f;
    f32x4 accC[4][2];
    #pragma unroll
    for (int mi = 0; mi < 4; ++mi)
        #pragma unroll
        for (int reg = 0; reg < 4; ++reg) { accC[mi][0][reg] = bias0; accC[mi][1][reg] = bias1; }
    f32x4 accY[8];
    #pragma unroll
    for (int yi = 0; yi < 8; ++yi) accY[yi] = (f32x4){0.f, 0.f, 0.f, 0.f};

    #pragma unroll
    for (int half = 0; half < 2; ++half) {
        const int cc0 = half * 32;
        const int koff = lk * 16;

        #pragma unroll
        for (int tap = 0; tap < 9; ++tap) {
            const int kh = tap / 3, kw = tap % 3;
            bf16x8 b0 = *(const bf16x8*)(smem + FOFF_BC + (size_t)(tap * 20 + lr) * 144 + (cc0 + lk * 8) * 2);
            int o1f = 16 + lr; if (o1f > 19) o1f = 19;
            bf16x8 b1 = *(const bf16x8*)(smem + FOFF_BC + (size_t)(tap * 20 + o1f) * 144 + (cc0 + lk * 8) * 2);
            #pragma unroll
            for (int mi = 0; mi < 4; ++mi) {
                int row  = 4 * w + mi;
                int cell = (row + kh + S) * PT + (lr + kw + S);
                bf16x8 a = *(const bf16x8*)(smem + FOFF_SX + SWZ(cell * 64 + koff));
                accC[mi][0] = __builtin_amdgcn_mfma_f32_16x16x32_bf16(a, b0, accC[mi][0], 0, 0, 0);
                accC[mi][1] = __builtin_amdgcn_mfma_f32_16x16x32_bf16(a, b1, accC[mi][1], 0, 0, 0);
            }
        }

        bf16x8 bY = *(const bf16x8*)(smem + FOFF_DW + (size_t)lr * 144 + (cc0 + lk * 8) * 2);
        #pragma unroll
        for (int yi = 0; yi < 8; ++yi) {
            int tile = 8 * w + yi;
            if (tile < 31) {
                int cell = tile * 16 + lr; if (cell > NCELL - 1) cell = NCELL - 1;
                bf16x8 a = *(const bf16x8*)(smem + FOFF_SX + SWZ(cell * 64 + koff));
                accY[yi] = __builtin_amdgcn_mfma_f32_16x16x32_bf16(a, bY, accY[yi], 0, 0, 0);
            }
        }

        if (half == 0) {
            __syncthreads();
            stage_x(32);
            __syncthreads();
        }
    }

    __syncthreads();

    float* s_off = (float*)(smem + FOFF_SOFF);
    float* s_Y   = (float*)(smem + FOFF_SY);
    #pragma unroll
    for (int mi = 0; mi < 4; ++mi) {
        #pragma unroll
        for (int nt = 0; nt < 2; ++nt) {
            int o = nt * 16 + lr;
            if (o < NOFF) {
                int pbase = (4 * w + mi) * 16 + lk * 4;
                #pragma unroll
                for (int reg = 0; reg < 4; ++reg)
                    s_off[o * 257 + pbase + reg] = accC[mi][nt][reg];
            }
        }
    }
    #pragma unroll
    for (int yi = 0; yi < 8; ++yi) {
        int tile = 8 * w + yi;
        if (tile < 31 && lr < KK) {
            #pragma unroll
            for (int reg = 0; reg < 4; ++reg) {
                int cell = tile * 16 + lk * 4 + reg;
                if (cell < NCELL) s_Y[lr * 485 + cell] = accY[yi][reg];
            }
        }
    }
    __syncthreads();

    const int ty = tid >> 4, tx = tid & 15;
    const int ho = y0 + ty, wo = x0 + tx;
    if (ho >= HO || wo >= WO) return;

    float acc = deform_b[0];

    #pragma unroll
    for (int k = 0; k < KK; ++k) {
        const int kh = k / 3, kw = k % 3;
        float dy = s_off[(2 * k) * 257 + tid];
        float dx = s_off[(2 * k + 1) * 257 + tid];
        float py = (float)(ho + kh) + dy;
        float px = (float)(wo + kw) + dx;
        float y0f = floorf(py), x0f = floorf(px);
        float ly = py - y0f, lx = px - x0f;
        int yi0 = (int)y0f, xi0 = (int)x0f;
        int ry = yi0 - (y0 - S);
        int rx = xi0 - (x0 - S);
        float w00 = (1.0f - ly) * (1.0f - lx);
        float w01 = (1.0f - ly) * lx;
        float w10 = ly * (1.0f - lx);
        float w11 = ly * lx;
        float g;
        if ((unsigned)ry <= (unsigned)(PT - 2) && (unsigned)rx <= (unsigned)(PT - 2)) {
            const float* tp = s_Y + k * 485;
            int id = ry * PT + rx;
            g = w00 * tp[id]      + w01 * tp[id + 1]
              + w10 * tp[id + PT] + w11 * tp[id + PT + 1];
        } else {
            int yi1 = yi0 + 1, xi1 = xi0 + 1;
            float m00 = (yi0 >= 0 && yi0 < HH && xi0 >= 0 && xi0 < WW) ? w00 : 0.0f;
            float m01 = (yi0 >= 0 && yi0 < HH && xi1 >= 0 && xi1 < WW) ? w01 : 0.0f;
            float m10 = (yi1 >= 0 && yi1 < HH && xi0 >= 0 && xi0 < WW) ? w10 : 0.0f;
            float m11 = (yi1 >= 0 && yi1 < HH && xi1 >= 0 && xi1 < WW) ? w11 : 0.0f;
            int y0cl = min(max(yi0, 0), HH - 1), y1cl = min(max(yi1, 0), HH - 1);
            int x0cl = min(max(xi0, 0), WW - 1), x1cl = min(max(xi1, 0), WW - 1);
            g = 0.0f;
            for (int c = 0; c < CC; ++c) {
                const float* xc = xb + (size_t)c * (HH * WW);
                float gc = m00 * xc[y0cl * WW + x0cl] + m01 * xc[y0cl * WW + x1cl]
                         + m10 * xc[y1cl * WW + x0cl] + m11 * xc[y1cl * WW + x1cl];
                gc *= deform_w[(size_t)c * KK + k];
                g += gc;
            }
        }
        acc += g;
    }

    out[(size_t)b * (HO * WO) + ho * WO + wo] = acc;
}

extern "C" void kernel_launch(void* const* d_in, const int* in_sizes, int n_in,
                              void* d_out, int out_size, void* d_ws, size_t ws_size,
                              hipStream_t stream) {
    const float* x        = (const float*)d_in[0];
    const float* offset_w = (const float*)d_in[1];
    const float* offset_b = (const float*)d_in[2];
    const float* deform_w = (const float*)d_in[3];
    const float* deform_b = (const float*)d_in[4];
    float* out = (float*)d_out;

    if (ws_size >= WS_NEED_F) {
        unsigned char* ws = (unsigned char*)d_ws;
        unsigned short* xT = (unsigned short*)(ws + WS_XT_F);

        hipLaunchKernelGGL(transpose_kernel, dim3(4, 256, BB), dim3(256), 0, stream,
                           x, xT, offset_w, deform_w, ws);
        hipLaunchKernelGGL(conv_gather_fused, dim3(16, 16, BB), dim3(256), 0, stream,
                           xT, offset_b, ws, deform_w, deform_b, out);
    } else if (ws_size >= (size_t)WS_NEED) {
        unsigned char* ws = (unsigned char*)d_ws;
        float* off = (float*)(ws + WS_OFF);
        float* Y   = (float*)(ws + WS_Y);

        hipLaunchKernelGGL(repack_kernel, dim3(10), dim3(256), 0, stream,
                           offset_w, deform_w, ws);
        hipLaunchKernelGGL(convY_kernel, dim3(512), dim3(256), 0, stream,
                           x, offset_b, ws, off, Y);
        hipLaunchKernelGGL(gather_kernel, dim3((NPIX + 255) / 256, BB), dim3(256), 0, stream,
                           off, Y, deform_b, out);
    } else {
        dim3 block(256);
        dim3 grid((WO + TS - 1) / TS, (HO + TS - 1) / TS, BB);
        hipLaunchKernelGGL(deform_fused_fallback, grid, block, 0, stream,
                           x, offset_w, offset_b, deform_w, deform_b, out);
    }
}